// Round 4
// baseline (147.545 us; speedup 1.0000x reference)
//
#include <hip/hip_runtime.h>
#include <math.h>

#define EPS      0.1f
#define INV_EPS  10.0f
#define THRESH   0.1f
#define MAX_IT   20

// Problem sizes (fixed by reference setup_inputs)
#define BB 4
#define NN 1024
#define MM 1024
#define DD 512

#define MU_P (1.0f / 1024.0f + 1e-8f)

// Fused gemm+sinkhorn: 256 blocks x 512 threads, 1 block/CU, 16 rows/block
#define GBLK 256
#define TBLK 512

// workspace layout (float offsets) — no global K buffer
#define OFF_XB   ((size_t)0)               // x in bf16 [B,N,D] (4.2 MB)
#define OFF_YB   ((size_t)1048576)         // y in bf16 [B,M,D] (4.2 MB)
#define OFF_NX   ((size_t)2097152)         // |x_i| [B*N]
#define OFF_NY   (OFF_NX + 4096)           // |y_j| [B*M]
#define OFF_NUP  (OFF_NY + 4096)           // nu + 1e-8 [B*M]
#define OFF_CS   (OFF_NUP + 4096)          // colsum rotation [3][4096]
#define OFF_FLG  (OFF_CS + 12288)          // barrier flags [2][256] ulong (4 KB)

typedef __bf16 bf16x8 __attribute__((ext_vector_type(8)));
typedef float f32x4 __attribute__((ext_vector_type(4)));
typedef unsigned long long u64;

__device__ __forceinline__ float wave_reduce_sum(float x) {
#pragma unroll
  for (int off = 32; off > 0; off >>= 1) x += __shfl_xor(x, off, 64);
  return x;
}

// pack two floats to bf16x2 (RNE via compiler cast)
__device__ __forceinline__ uint pk2(float a, float b) {
  __bf16 ha = (__bf16)a, hb = (__bf16)b;
  return (uint)*(ushort*)&ha | ((uint)*(ushort*)&hb << 16);
}

__device__ __forceinline__ void unpack8(uint4 k, float* kf) {
  kf[0] = __uint_as_float(k.x << 16);
  kf[1] = __uint_as_float(k.x & 0xffff0000u);
  kf[2] = __uint_as_float(k.y << 16);
  kf[3] = __uint_as_float(k.y & 0xffff0000u);
  kf[4] = __uint_as_float(k.z << 16);
  kf[5] = __uint_as_float(k.z & 0xffff0000u);
  kf[6] = __uint_as_float(k.w << 16);
  kf[7] = __uint_as_float(k.w & 0xffff0000u);
}

// -------- prep: fp32 norms of x/y rows, x/y -> bf16, sinkhorn state init.
// Kernel boundary after this = device-scope release (proven rounds 0-2). --------
__global__ void __launch_bounds__(256) prep_kernel(const float* __restrict__ x,
                                                   const float* __restrict__ y,
                                                   ushort* __restrict__ xb,
                                                   ushort* __restrict__ yb,
                                                   float* __restrict__ nx,
                                                   float* __restrict__ ny,
                                                   const float* __restrict__ nu,
                                                   float* nup, float* colsum,
                                                   int* flagsi, float* out) {
  const int tid = threadIdx.x;
  int gt = blockIdx.x * 256 + tid;
  if (gt < BB * MM) {
    nup[gt] = nu[gt] + 1e-8f;
    colsum[4096 + gt] = 0.f;      // buf1 is iteration 0's add target
  }
  if (gt < 1024) flagsi[gt] = 0;  // 2 x 256 ulong flag slots
  if (gt < BB) out[gt] = 0.f;

  const int w = tid >> 6, lane = tid & 63;
  const int r = blockIdx.x * 4 + w;                 // 0..8191
  const bool isx = (r < BB * NN);
  const float* src = isx ? (x + (size_t)r * DD)
                         : (y + (size_t)(r - BB * NN) * DD);
  ushort* dst = isx ? (xb + (size_t)r * DD)
                    : (yb + (size_t)(r - BB * NN) * DD);
  const float4* s4 = (const float4*)src;
  float4 a = s4[lane * 2];          // 8 contiguous floats per lane
  float4 b = s4[lane * 2 + 1];
  float ss = a.x * a.x + a.y * a.y + a.z * a.z + a.w * a.w +
             b.x * b.x + b.y * b.y + b.z * b.z + b.w * b.w;
  uint4 pk = make_uint4(pk2(a.x, a.y), pk2(a.z, a.w), pk2(b.x, b.y), pk2(b.z, b.w));
  *(uint4*)(dst + lane * 8) = pk;
  ss = wave_reduce_sum(ss);
  if (lane == 0) {
    float n = sqrtf(ss);
    if (isx) nx[r] = n; else ny[r - BB * NN] = n;
  }
}

// -------- fused strip-GEMM + persistent Sinkhorn (cooperative) --------
// phase 1: each block computes its own 16 K-rows (16x1024) into LDS via MFMA
//          (A in 64 VGPRs, B streamed from XCD-local L2); K never hits global.
// phase 2: proven sinkhorn loop (rounds 0-2), 2 rows/wave in 32 VGPRs.
__global__ void __launch_bounds__(TBLK, 2) fused_kernel(
    const ushort* __restrict__ xb, const ushort* __restrict__ yb,
    const float* __restrict__ nx, const float* __restrict__ ny,
    float* __restrict__ colsum, const float* __restrict__ nup,
    u64* __restrict__ flags, float* __restrict__ out) {
  const int tid = threadIdx.x;
  const int bid = blockIdx.x;
  const int lane = tid & 63;
  const int w = tid >> 6;                 // 0..7
  const int m16 = lane & 15, q = lane >> 4;
  // XCD-aware (bid%8 == XCD round-robin): 2 XCDs own one batch -> each XCD's
  // L2 caches only that batch's 1 MB of Y during the strip GEMM. Perf-only.
  const int sbid = (bid & 7) * 32 + (bid >> 3);   // bijective on [0,256)
  const int batch = sbid >> 6;                    // 64 blocks per batch
  const int rbase = (sbid & 63) * 16;             // 16 owned rows

  __shared__ alignas(16) ushort kstrip[16 * 1024];  // 32 KB; aliased as spart
  __shared__ alignas(16) float s_v[1024];           // ny norms, then wv
  __shared__ float s_nx[16];
  __shared__ float s_red;
  __shared__ int s_conv;
  float* spart = (float*)kstrip;                    // [8][1024] after GEMM

  // ---------------- phase 1: strip GEMM into LDS ----------------
  {
    if (tid < 16) s_nx[tid] = nx[batch * NN + rbase + tid];
    s_v[tid] = ny[batch * MM + tid];
    s_v[tid + 512] = ny[batch * MM + tid + 512];

    bf16x8 afr[16];
    const ushort* arow = xb + ((size_t)batch * NN + rbase + m16) * DD + q * 8;
#pragma unroll
    for (int k = 0; k < 16; ++k) afr[k] = *(const bf16x8*)(arow + k * 32);

    const int j0 = w * 128;
    const ushort* brow = yb + ((size_t)batch * MM + j0 + m16) * DD + q * 8;
    f32x4 acc[8];
#pragma unroll
    for (int ni = 0; ni < 8; ++ni) acc[ni] = (f32x4)0.f;
#pragma unroll
    for (int k = 0; k < 16; ++k) {
      bf16x8 bfr[8];
#pragma unroll
      for (int ni = 0; ni < 8; ++ni)
        bfr[ni] = *(const bf16x8*)(brow + (size_t)ni * 16 * DD + k * 32);
#pragma unroll
      for (int ni = 0; ni < 8; ++ni)
        acc[ni] = __builtin_amdgcn_mfma_f32_16x16x32_bf16(afr[k], bfr[ni], acc[ni], 0, 0, 0);
    }
    __syncthreads();   // s_nx/s_v staged before epilogue reads

    // epilogue: K = exp(-(1 - dot/den)/eps) -> LDS bf16
#pragma unroll
    for (int ni = 0; ni < 8; ++ni)
#pragma unroll
      for (int r = 0; r < 4; ++r) {
        const int row = q * 4 + r;
        const int col = j0 + ni * 16 + m16;
        float den = fmaxf(s_nx[row] * s_v[col], 1e-8f);
        float cv = 1.0f - acc[ni][r] / den;
        float kv = __expf(-cv * INV_EPS);
        __bf16 hb = (__bf16)kv;
        kstrip[row * 1024 + col] = *(ushort*)&hb;
      }
    __syncthreads();   // strip complete before per-wave reg loads
  }

  // ---- each wave loads its 2 rows into registers (32 VGPR), fp32 ----
  float kfr[2][16];
  {
    const int r0 = 2 * w;
    uint4 p;
    p = *(const uint4*)&kstrip[r0 * 1024 + 8 * lane];             unpack8(p, kfr[0]);
    p = *(const uint4*)&kstrip[r0 * 1024 + 512 + 8 * lane];       unpack8(p, kfr[0] + 8);
    p = *(const uint4*)&kstrip[(r0 + 1) * 1024 + 8 * lane];       unpack8(p, kfr[1]);
    p = *(const uint4*)&kstrip[(r0 + 1) * 1024 + 512 + 8 * lane]; unpack8(p, kfr[1] + 8);
  }
  // kstrip memory is reused as spart[8][1024] from here on; the
  // __syncthreads() after wv staging in iteration 0 orders writes after the
  // kfr reads above (all threads pass that barrier after their ds_reads).

  // ---------------- phase 2: persistent Sinkhorn (proven) ----------------
  const float eps_log_mu = EPS * __logf(MU_P);
  float u_prev[2] = {0.f, 0.f};
  float wu_reg[2] = {0.f, 0.f};
  int T = 0;

  for (int it = 0; it < MAX_IT; ++it) {
    const int genv = it + 1;
    if (tid == 0) s_red = 0.f;
    if (it == 0) {
      s_v[tid] = 1.f;
      s_v[tid + 512] = 1.f;
    } else {
      const float* cs = colsum + (it % 3) * 4096 + batch * MM;
      float c0 = __hip_atomic_load(cs + tid, __ATOMIC_RELAXED, __HIP_MEMORY_SCOPE_AGENT);
      float c1 = __hip_atomic_load(cs + tid + 512, __ATOMIC_RELAXED, __HIP_MEMORY_SCOPE_AGENT);
      s_v[tid] = nup[batch * MM + tid] / c0;
      s_v[tid + 512] = nup[batch * MM + tid + 512] / c1;
    }
    __syncthreads();

    float wvr[16];
    {
      const float4* wp = (const float4*)s_v;
      *(float4*)&wvr[0] = wp[lane * 2];
      *(float4*)&wvr[4] = wp[lane * 2 + 1];
      *(float4*)&wvr[8] = wp[128 + lane * 2];
      *(float4*)&wvr[12] = wp[129 + lane * 2];
    }
    float creg[16];
#pragma unroll
    for (int t2 = 0; t2 < 16; ++t2) creg[t2] = 0.f;

    float werr = 0.f;
#pragma unroll
    for (int rr = 0; rr < 2; ++rr) {
      float s = 0.f;
#pragma unroll
      for (int t2 = 0; t2 < 16; ++t2) s = fmaf(kfr[rr][t2], wvr[t2], s);
      s = wave_reduce_sum(s);
      float unv = eps_log_mu - EPS * __logf(s);
      werr += fabsf(unv - u_prev[rr]);
      u_prev[rr] = unv;
      float wu = MU_P / s;              // exp(u_new/eps), exactly
      wu_reg[rr] = wu;
#pragma unroll
      for (int t2 = 0; t2 < 16; ++t2) creg[t2] = fmaf(wu, kfr[rr][t2], creg[t2]);
    }
    if (lane == 0) atomicAdd(&s_red, werr);

    // publish per-wave column partials to LDS (aliased kstrip)
    {
      float* pr = spart + w * 1024;
      *(float4*)&pr[lane * 8] = *(float4*)&creg[0];
      *(float4*)&pr[lane * 8 + 4] = *(float4*)&creg[4];
      *(float4*)&pr[512 + lane * 8] = *(float4*)&creg[8];
      *(float4*)&pr[512 + lane * 8 + 4] = *(float4*)&creg[12];
    }
    __syncthreads();

    // cross-wave reduce + atomic add into next colsum; zero rotation buffer
    {
      float* csn = colsum + ((it + 1) % 3) * 4096 + batch * MM;
      const int j0 = tid * 2;
      float s0 = 0.f, s1 = 0.f;
#pragma unroll
      for (int ww = 0; ww < 8; ++ww) {
        float2 p = *(const float2*)&spart[ww * 1024 + j0];
        s0 += p.x;
        s1 += p.y;
      }
      unsafeAtomicAdd(&csn[j0], s0);
      unsafeAtomicAdd(&csn[j0 + 1], s1);
      if (tid < 16) {
        float* csz = colsum + ((it + 2) % 3) * 4096;
        __hip_atomic_store(&csz[bid * 16 + tid], 0.f, __ATOMIC_RELAXED, __HIP_MEMORY_SCOPE_AGENT);
      }
    }

    // ---- all-to-all barrier: publish {gen, err}, poll, local conv decision ----
    asm volatile("s_waitcnt vmcnt(0)" ::: "memory");
    __syncthreads();
    if (tid == 0) {
      u64 f = ((u64)(uint)genv << 32) | (u64)__float_as_uint(s_red);
      __hip_atomic_store(&flags[(genv & 1) * GBLK + bid], f, __ATOMIC_RELAXED, __HIP_MEMORY_SCOPE_AGENT);
    }
    if (tid < 64) {
      const u64* fl = flags + (genv & 1) * GBLK;
      u64 f0, f1, f2, f3;
      for (;;) {
        f0 = __hip_atomic_load(fl + tid, __ATOMIC_RELAXED, __HIP_MEMORY_SCOPE_AGENT);
        f1 = __hip_atomic_load(fl + tid + 64, __ATOMIC_RELAXED, __HIP_MEMORY_SCOPE_AGENT);
        f2 = __hip_atomic_load(fl + tid + 128, __ATOMIC_RELAXED, __HIP_MEMORY_SCOPE_AGENT);
        f3 = __hip_atomic_load(fl + tid + 192, __ATOMIC_RELAXED, __HIP_MEMORY_SCOPE_AGENT);
        if (__all(((f0 >> 32) >= (u64)genv) && ((f1 >> 32) >= (u64)genv) &&
                  ((f2 >> 32) >= (u64)genv) && ((f3 >> 32) >= (u64)genv))) break;
        __builtin_amdgcn_s_sleep(1);
      }
      float e = __uint_as_float((uint)f0) + __uint_as_float((uint)f1) +
                __uint_as_float((uint)f2) + __uint_as_float((uint)f3);
      e = wave_reduce_sum(e);
      if (tid == 0) s_conv = (e * (1.0f / (float)BB) < THRESH) ? 1 : 0;
    }
    __syncthreads();
    T = it;
    if (s_conv) break;
  }

  // ---- final: reconstruct converged wv locally, accumulate transport cost ----
  {
    const float* cs = colsum + ((T + 1) % 3) * 4096 + batch * MM;
    float c0 = __hip_atomic_load(cs + tid, __ATOMIC_RELAXED, __HIP_MEMORY_SCOPE_AGENT);
    float c1 = __hip_atomic_load(cs + tid + 512, __ATOMIC_RELAXED, __HIP_MEMORY_SCOPE_AGENT);
    s_v[tid] = nup[batch * MM + tid] / c0;
    s_v[tid + 512] = nup[batch * MM + tid + 512] / c1;
  }
  if (tid == 0) s_red = 0.f;
  __syncthreads();

  float wvr[16];
  {
    const float4* wp = (const float4*)s_v;
    *(float4*)&wvr[0] = wp[lane * 2];
    *(float4*)&wvr[4] = wp[lane * 2 + 1];
    *(float4*)&wvr[8] = wp[128 + lane * 2];
    *(float4*)&wvr[12] = wp[129 + lane * 2];
  }

  float wcost = 0.f;
#pragma unroll
  for (int rr = 0; rr < 2; ++rr) {
    float s = 0.f;
#pragma unroll
    for (int t2 = 0; t2 < 16; ++t2)
      s = fmaf(kfr[rr][t2] * wvr[t2], -EPS * __logf(kfr[rr][t2]), s);  // pi*C, C=-eps log K
    s = wave_reduce_sum(s) * wu_reg[rr];
    if (lane == 0) wcost += s;
  }
  if (lane == 0) atomicAdd(&s_red, wcost);
  __syncthreads();
  if (tid == 0) atomicAdd(out + batch, s_red);
}

extern "C" void kernel_launch(void* const* d_in, const int* in_sizes, int n_in,
                              void* d_out, int out_size, void* d_ws, size_t ws_size,
                              hipStream_t stream) {
  const float* x = (const float*)d_in[0];
  const float* y = (const float*)d_in[1];
  const float* nu = (const float*)d_in[2];
  float* out = (float*)d_out;
  float* ws = (float*)d_ws;

  ushort* xb = (ushort*)(ws + OFF_XB);
  ushort* yb = (ushort*)(ws + OFF_YB);
  float* nx = ws + OFF_NX;
  float* ny = ws + OFF_NY;
  float* nup = ws + OFF_NUP;
  float* cs = ws + OFF_CS;
  u64* flg = (u64*)(ws + OFF_FLG);

  prep_kernel<<<2048, 256, 0, stream>>>(x, y, xb, yb, nx, ny, nu, nup, cs,
                                        (int*)flg, out);

  void* args[] = {(void*)&xb, (void*)&yb, (void*)&nx,  (void*)&ny,
                  (void*)&cs, (void*)&nup, (void*)&flg, (void*)&out};
  hipLaunchCooperativeKernel(reinterpret_cast<void*>(&fused_kernel),
                             dim3(GBLK), dim3(TBLK), args, 0, stream);
}

// Round 5
// 139.173 us; speedup vs baseline: 1.0602x; 1.0602x over previous
//
#include <hip/hip_runtime.h>
#include <math.h>

#define EPS      0.1f
#define INV_EPS  10.0f
#define THRESH   0.1f
#define MAX_IT   20

// Problem sizes (fixed by reference setup_inputs)
#define BB 4
#define NN 1024
#define MM 1024
#define DD 512

#define MU_P (1.0f / 1024.0f + 1e-8f)

// Fused gemm+sinkhorn: 128 blocks x 512 threads (PROVEN sinkhorn config:
// 128 barrier participants, 32 atomic writers/address, 4 rows/wave).
#define GBLK 128
#define TBLK 512

// workspace layout (float offsets) — no global K buffer
#define OFF_XB   ((size_t)0)               // x in bf16 [B,N,D] (4.2 MB)
#define OFF_YB   ((size_t)1048576)         // y in bf16 [B,M,D] (4.2 MB)
#define OFF_NX   ((size_t)2097152)         // |x_i| [B*N]
#define OFF_NY   (OFF_NX + 4096)           // |y_j| [B*M]
#define OFF_NUP  (OFF_NY + 4096)           // nu + 1e-8 [B*M]
#define OFF_CS   (OFF_NUP + 4096)          // colsum rotation [3][4096]
#define OFF_FLG  (OFF_CS + 12288)          // barrier flags [2][128] ulong

#define ALDA 520   // padded A-stage stride (halves): bank-optimal b128 frag reads
#define KLDA 1032  // padded K-strip stride (halves)

typedef __bf16 bf16x8 __attribute__((ext_vector_type(8)));
typedef float f32x4 __attribute__((ext_vector_type(4)));
typedef unsigned long long u64;

__device__ __forceinline__ float wave_reduce_sum(float x) {
#pragma unroll
  for (int off = 32; off > 0; off >>= 1) x += __shfl_xor(x, off, 64);
  return x;
}

// pack two floats to bf16x2 (RNE via compiler cast)
__device__ __forceinline__ uint pk2(float a, float b) {
  __bf16 ha = (__bf16)a, hb = (__bf16)b;
  return (uint)*(ushort*)&ha | ((uint)*(ushort*)&hb << 16);
}

__device__ __forceinline__ void unpack8(uint4 k, float* kf) {
  kf[0] = __uint_as_float(k.x << 16);
  kf[1] = __uint_as_float(k.x & 0xffff0000u);
  kf[2] = __uint_as_float(k.y << 16);
  kf[3] = __uint_as_float(k.y & 0xffff0000u);
  kf[4] = __uint_as_float(k.z << 16);
  kf[5] = __uint_as_float(k.z & 0xffff0000u);
  kf[6] = __uint_as_float(k.w << 16);
  kf[7] = __uint_as_float(k.w & 0xffff0000u);
}

// -------- prep: fp32 norms of x/y rows, x/y -> bf16, sinkhorn state init.
// Kernel boundary after this = device-scope release (proven rounds 0-2, 4). --------
__global__ void __launch_bounds__(256) prep_kernel(const float* __restrict__ x,
                                                   const float* __restrict__ y,
                                                   ushort* __restrict__ xb,
                                                   ushort* __restrict__ yb,
                                                   float* __restrict__ nx,
                                                   float* __restrict__ ny,
                                                   const float* __restrict__ nu,
                                                   float* nup, float* colsum,
                                                   int* flagsi, float* out) {
  const int tid = threadIdx.x;
  int gt = blockIdx.x * 256 + tid;
  if (gt < BB * MM) {
    nup[gt] = nu[gt] + 1e-8f;
    colsum[4096 + gt] = 0.f;      // buf1 is iteration 0's add target
  }
  if (gt < 512) flagsi[gt] = 0;   // 2 x 128 ulong flag slots
  if (gt < BB) out[gt] = 0.f;

  const int w = tid >> 6, lane = tid & 63;
  const int r = blockIdx.x * 4 + w;                 // 0..8191
  const bool isx = (r < BB * NN);
  const float* src = isx ? (x + (size_t)r * DD)
                         : (y + (size_t)(r - BB * NN) * DD);
  ushort* dst = isx ? (xb + (size_t)r * DD)
                    : (yb + (size_t)(r - BB * NN) * DD);
  const float4* s4 = (const float4*)src;
  float4 a = s4[lane * 2];          // 8 contiguous floats per lane
  float4 b = s4[lane * 2 + 1];
  float ss = a.x * a.x + a.y * a.y + a.z * a.z + a.w * a.w +
             b.x * b.x + b.y * b.y + b.z * b.z + b.w * b.w;
  uint4 pk = make_uint4(pk2(a.x, a.y), pk2(a.z, a.w), pk2(b.x, b.y), pk2(b.z, b.w));
  *(uint4*)(dst + lane * 8) = pk;
  ss = wave_reduce_sum(ss);
  if (lane == 0) {
    float n = sqrtf(ss);
    if (isx) nx[r] = n; else ny[r - BB * NN] = n;
  }
}

// -------- fused strip-GEMM + persistent Sinkhorn (cooperative) --------
// phase 1: block computes its 32 K-rows (32x1024) into LDS via MFMA
//          (A staged in LDS, B streamed from XCD-local L2); K never hits global.
// phase 2: EXACT round-1 sinkhorn (128 participants, 4 rows/wave in 64 VGPRs).
__global__ void __launch_bounds__(TBLK, 2) fused_kernel(
    const ushort* __restrict__ xb, const ushort* __restrict__ yb,
    const float* __restrict__ nx, const float* __restrict__ ny,
    float* __restrict__ colsum, const float* __restrict__ nup,
    u64* __restrict__ flags, float* __restrict__ out) {
  const int tid = threadIdx.x;
  const int bid = blockIdx.x;
  const int lane = tid & 63;
  const int w = tid >> 6;                 // 0..7
  const int m16 = lane & 15, q = lane >> 4;
  // XCD-aware (bid%8 == XCD round-robin): 2 XCDs per batch -> each XCD's L2
  // caches only its batch's 1 MB of Y during the strip GEMM. Perf-only.
  const int sbid = (bid & 7) * 16 + (bid >> 3);   // bijective on [0,128)
  const int batch = sbid >> 5;                    // 32 blocks per batch
  const int rbase = (sbid & 31) * 32;             // 32 owned rows

  __shared__ alignas(16) ushort As[32 * ALDA];      // 33.3 KB padded A stage
  __shared__ alignas(16) ushort kstrip[32 * KLDA];  // 66 KB K strip; spart alias
  __shared__ alignas(16) float s_v[1024];           // ny norms, then wv
  __shared__ float s_nx[32];
  __shared__ float s_red;
  __shared__ int s_conv;
  float* spart = (float*)kstrip;                    // [8][1024] in sinkhorn phase

  // ---------------- phase 1: strip GEMM into LDS ----------------
  {
    if (tid < 32) s_nx[tid] = nx[batch * NN + rbase + tid];
    s_v[tid] = ny[batch * MM + tid];
    s_v[tid + 512] = ny[batch * MM + tid + 512];

    // stage A strip (32 rows x 512 halves, contiguous in xb) into padded LDS
    {
      const ushort* xs = xb + ((size_t)batch * NN + rbase) * DD;
      const int row = tid >> 4;          // 16 threads per row
      const int c0 = (tid & 15) * 32;    // 32 halves (2 uint4 pairs x 2) each
#pragma unroll
      for (int i = 0; i < 4; ++i) {
        uint4 v = *(const uint4*)(xs + (size_t)row * DD + c0 + i * 8);
        *(uint4*)&As[row * ALDA + c0 + i * 8] = v;
      }
    }
    __syncthreads();

    // wave w owns cols [w*128, w*128+128), all 32 rows (2 row-tiles)
    const int j0 = w * 128;
    const ushort* brow = yb + ((size_t)batch * MM + j0 + m16) * DD + q * 8;
    f32x4 acc[2][8];
#pragma unroll
    for (int rt = 0; rt < 2; ++rt)
#pragma unroll
      for (int ni = 0; ni < 8; ++ni) acc[rt][ni] = (f32x4)0.f;

#pragma unroll
    for (int ks = 0; ks < 16; ++ks) {
      bf16x8 a0 = *(const bf16x8*)&As[(m16)*ALDA + ks * 32 + q * 8];
      bf16x8 a1 = *(const bf16x8*)&As[(16 + m16) * ALDA + ks * 32 + q * 8];
      bf16x8 bfr[8];
#pragma unroll
      for (int ni = 0; ni < 8; ++ni)
        bfr[ni] = *(const bf16x8*)(brow + (size_t)ni * 16 * DD + ks * 32);
#pragma unroll
      for (int ni = 0; ni < 8; ++ni)
        acc[0][ni] = __builtin_amdgcn_mfma_f32_16x16x32_bf16(a0, bfr[ni], acc[0][ni], 0, 0, 0);
#pragma unroll
      for (int ni = 0; ni < 8; ++ni)
        acc[1][ni] = __builtin_amdgcn_mfma_f32_16x16x32_bf16(a1, bfr[ni], acc[1][ni], 0, 0, 0);
    }

    // epilogue: K = exp(-(1 - dot/den)/eps) -> LDS bf16 (kstrip region untouched
    // so far; As is dead; s_nx/s_v were staged before the first barrier)
#pragma unroll
    for (int rt = 0; rt < 2; ++rt)
#pragma unroll
      for (int ni = 0; ni < 8; ++ni)
#pragma unroll
        for (int r = 0; r < 4; ++r) {
          const int row = rt * 16 + q * 4 + r;
          const int col = j0 + ni * 16 + m16;
          float den = fmaxf(s_nx[row] * s_v[col], 1e-8f);
          float cv = 1.0f - acc[rt][ni][r] / den;
          float kv = __expf(-cv * INV_EPS);
          __bf16 hb = (__bf16)kv;
          kstrip[row * KLDA + col] = *(ushort*)&hb;
        }
    __syncthreads();   // strip complete before cross-wave per-wave reg loads
  }

  // ---- each wave loads its 4 rows into registers (64 VGPR), fp32 ----
  float kfr[4][16];
#pragma unroll
  for (int rr = 0; rr < 4; ++rr) {
    const int base = (w * 4 + rr) * KLDA;
    uint4 p;
    p = *(const uint4*)&kstrip[base + 8 * lane];       unpack8(p, kfr[rr]);
    p = *(const uint4*)&kstrip[base + 512 + 8 * lane]; unpack8(p, kfr[rr] + 8);
  }
  // kstrip memory is reused as spart[8][1024] from here on; the __syncthreads()
  // after wv staging in iteration 0 orders spart writes after the kfr reads.

  // ---------------- phase 2: persistent Sinkhorn (round-1 verbatim) ----------------
  const float eps_log_mu = EPS * __logf(MU_P);
  float u_prev[4] = {0.f, 0.f, 0.f, 0.f};
  float wu_reg[4] = {0.f, 0.f, 0.f, 0.f};
  int T = 0;

  for (int it = 0; it < MAX_IT; ++it) {
    const int genv = it + 1;
    if (tid == 0) s_red = 0.f;
    if (it == 0) {
      s_v[tid] = 1.f;
      s_v[tid + 512] = 1.f;
    } else {
      const float* cs = colsum + (it % 3) * 4096 + batch * MM;
      float c0 = __hip_atomic_load(cs + tid, __ATOMIC_RELAXED, __HIP_MEMORY_SCOPE_AGENT);
      float c1 = __hip_atomic_load(cs + tid + 512, __ATOMIC_RELAXED, __HIP_MEMORY_SCOPE_AGENT);
      s_v[tid] = nup[batch * MM + tid] / c0;
      s_v[tid + 512] = nup[batch * MM + tid + 512] / c1;
    }
    __syncthreads();

    float wvr[16];
    {
      const float4* wp = (const float4*)s_v;
      *(float4*)&wvr[0] = wp[lane * 2];
      *(float4*)&wvr[4] = wp[lane * 2 + 1];
      *(float4*)&wvr[8] = wp[128 + lane * 2];
      *(float4*)&wvr[12] = wp[129 + lane * 2];
    }
    float creg[16];
#pragma unroll
    for (int t2 = 0; t2 < 16; ++t2) creg[t2] = 0.f;

    float werr = 0.f;
#pragma unroll
    for (int rr = 0; rr < 4; ++rr) {
      float s = 0.f;
#pragma unroll
      for (int t2 = 0; t2 < 16; ++t2) s = fmaf(kfr[rr][t2], wvr[t2], s);
      s = wave_reduce_sum(s);
      float unv = eps_log_mu - EPS * __logf(s);
      werr += fabsf(unv - u_prev[rr]);
      u_prev[rr] = unv;
      float wu = MU_P / s;              // exp(u_new/eps), exactly
      wu_reg[rr] = wu;
#pragma unroll
      for (int t2 = 0; t2 < 16; ++t2) creg[t2] = fmaf(wu, kfr[rr][t2], creg[t2]);
    }
    if (lane == 0) atomicAdd(&s_red, werr);

    // publish per-wave column partials to LDS (aliased kstrip)
    {
      float* pr = spart + w * 1024;
      *(float4*)&pr[lane * 8] = *(float4*)&creg[0];
      *(float4*)&pr[lane * 8 + 4] = *(float4*)&creg[4];
      *(float4*)&pr[512 + lane * 8] = *(float4*)&creg[8];
      *(float4*)&pr[512 + lane * 8 + 4] = *(float4*)&creg[12];
    }
    __syncthreads();

    // cross-wave reduce + atomic add into next colsum; zero rotation buffer
    {
      float* csn = colsum + ((it + 1) % 3) * 4096 + batch * MM;
      const int j0 = tid * 2;
      float s0 = 0.f, s1 = 0.f;
#pragma unroll
      for (int ww = 0; ww < 8; ++ww) {
        float2 p = *(const float2*)&spart[ww * 1024 + j0];
        s0 += p.x;
        s1 += p.y;
      }
      unsafeAtomicAdd(&csn[j0], s0);
      unsafeAtomicAdd(&csn[j0 + 1], s1);
      if (tid < 32) {
        float* csz = colsum + ((it + 2) % 3) * 4096;
        __hip_atomic_store(&csz[bid * 32 + tid], 0.f, __ATOMIC_RELAXED, __HIP_MEMORY_SCOPE_AGENT);
      }
    }

    // ---- all-to-all barrier: publish {gen, err}, poll, local conv decision ----
    asm volatile("s_waitcnt vmcnt(0)" ::: "memory");
    __syncthreads();
    if (tid == 0) {
      u64 f = ((u64)(uint)genv << 32) | (u64)__float_as_uint(s_red);
      __hip_atomic_store(&flags[(genv & 1) * GBLK + bid], f, __ATOMIC_RELAXED, __HIP_MEMORY_SCOPE_AGENT);
    }
    if (tid < 64) {
      const u64* fl = flags + (genv & 1) * GBLK;
      u64 f0, f1;
      for (;;) {
        f0 = __hip_atomic_load(fl + tid, __ATOMIC_RELAXED, __HIP_MEMORY_SCOPE_AGENT);
        f1 = __hip_atomic_load(fl + tid + 64, __ATOMIC_RELAXED, __HIP_MEMORY_SCOPE_AGENT);
        if (__all(((f0 >> 32) >= (u64)genv) && ((f1 >> 32) >= (u64)genv))) break;
        __builtin_amdgcn_s_sleep(1);
      }
      float e = __uint_as_float((uint)f0) + __uint_as_float((uint)f1);
      e = wave_reduce_sum(e);
      if (tid == 0) s_conv = (e * (1.0f / (float)BB) < THRESH) ? 1 : 0;
    }
    __syncthreads();
    T = it;
    if (s_conv) break;
  }

  // ---- final: reconstruct converged wv locally, accumulate transport cost ----
  {
    const float* cs = colsum + ((T + 1) % 3) * 4096 + batch * MM;
    float c0 = __hip_atomic_load(cs + tid, __ATOMIC_RELAXED, __HIP_MEMORY_SCOPE_AGENT);
    float c1 = __hip_atomic_load(cs + tid + 512, __ATOMIC_RELAXED, __HIP_MEMORY_SCOPE_AGENT);
    s_v[tid] = nup[batch * MM + tid] / c0;
    s_v[tid + 512] = nup[batch * MM + tid + 512] / c1;
  }
  if (tid == 0) s_red = 0.f;
  __syncthreads();

  float wvr[16];
  {
    const float4* wp = (const float4*)s_v;
    *(float4*)&wvr[0] = wp[lane * 2];
    *(float4*)&wvr[4] = wp[lane * 2 + 1];
    *(float4*)&wvr[8] = wp[128 + lane * 2];
    *(float4*)&wvr[12] = wp[129 + lane * 2];
  }

  float wcost = 0.f;
#pragma unroll
  for (int rr = 0; rr < 4; ++rr) {
    float s = 0.f;
#pragma unroll
    for (int t2 = 0; t2 < 16; ++t2)
      s = fmaf(kfr[rr][t2] * wvr[t2], -EPS * __logf(kfr[rr][t2]), s);  // pi*C, C=-eps log K
    s = wave_reduce_sum(s) * wu_reg[rr];
    if (lane == 0) wcost += s;
  }
  if (lane == 0) atomicAdd(&s_red, wcost);
  __syncthreads();
  if (tid == 0) atomicAdd(out + batch, s_red);
}

extern "C" void kernel_launch(void* const* d_in, const int* in_sizes, int n_in,
                              void* d_out, int out_size, void* d_ws, size_t ws_size,
                              hipStream_t stream) {
  const float* x = (const float*)d_in[0];
  const float* y = (const float*)d_in[1];
  const float* nu = (const float*)d_in[2];
  float* out = (float*)d_out;
  float* ws = (float*)d_ws;

  ushort* xb = (ushort*)(ws + OFF_XB);
  ushort* yb = (ushort*)(ws + OFF_YB);
  float* nx = ws + OFF_NX;
  float* ny = ws + OFF_NY;
  float* nup = ws + OFF_NUP;
  float* cs = ws + OFF_CS;
  u64* flg = (u64*)(ws + OFF_FLG);

  prep_kernel<<<2048, 256, 0, stream>>>(x, y, xb, yb, nx, ny, nu, nup, cs,
                                        (int*)flg, out);

  void* args[] = {(void*)&xb, (void*)&yb, (void*)&nx,  (void*)&ny,
                  (void*)&cs, (void*)&nup, (void*)&flg, (void*)&out};
  hipLaunchCooperativeKernel(reinterpret_cast<void*>(&fused_kernel),
                             dim3(GBLK), dim3(TBLK), args, 0, stream);
}

// Round 6
// 138.083 us; speedup vs baseline: 1.0685x; 1.0079x over previous
//
#include <hip/hip_runtime.h>
#include <math.h>

#define EPS      0.1f
#define INV_EPS  10.0f
#define THRESH   0.1f
#define MAX_IT   20

// Problem sizes (fixed by reference setup_inputs)
#define BB 4
#define NN 1024
#define MM 1024
#define DD 512

#define MU_P (1.0f / 1024.0f + 1e-8f)

// Fused gemm+sinkhorn: 128 blocks x 512 threads (PROVEN sinkhorn config:
// 128 barrier participants, 32 atomic writers/address, 4 rows/wave).
#define GBLK 128
#define TBLK 512

// workspace layout (float offsets) — no global K buffer
#define OFF_XB   ((size_t)0)               // x in bf16 [B,N,D] (4.2 MB)
#define OFF_YB   ((size_t)1048576)         // y in bf16 [B,M,D] (4.2 MB)
#define OFF_NX   ((size_t)2097152)         // |x_i| [B*N]
#define OFF_NY   (OFF_NX + 4096)           // |y_j| [B*M]
#define OFF_NUP  (OFF_NY + 4096)           // nu + 1e-8 [B*M]
#define OFF_CS   (OFF_NUP + 4096)          // colsum rotation [3][4096]
#define OFF_FLG  (OFF_CS + 12288)          // barrier flags [2][128] ulong

#define ALDA 520   // padded A-stage stride (halves): bank-optimal b128 frag reads
#define KLDA 1032  // padded K-strip stride (halves)

typedef __bf16 bf16x8 __attribute__((ext_vector_type(8)));
typedef float f32x4 __attribute__((ext_vector_type(4)));
typedef unsigned long long u64;

__device__ __forceinline__ float wave_reduce_sum(float x) {
#pragma unroll
  for (int off = 32; off > 0; off >>= 1) x += __shfl_xor(x, off, 64);
  return x;
}

// pack two floats to bf16x2 (RNE via compiler cast)
__device__ __forceinline__ uint pk2(float a, float b) {
  __bf16 ha = (__bf16)a, hb = (__bf16)b;
  return (uint)*(ushort*)&ha | ((uint)*(ushort*)&hb << 16);
}

__device__ __forceinline__ void unpack8(uint4 k, float* kf) {
  kf[0] = __uint_as_float(k.x << 16);
  kf[1] = __uint_as_float(k.x & 0xffff0000u);
  kf[2] = __uint_as_float(k.y << 16);
  kf[3] = __uint_as_float(k.y & 0xffff0000u);
  kf[4] = __uint_as_float(k.z << 16);
  kf[5] = __uint_as_float(k.z & 0xffff0000u);
  kf[6] = __uint_as_float(k.w << 16);
  kf[7] = __uint_as_float(k.w & 0xffff0000u);
}

// -------- prep: fp32 norms of x/y rows, x/y -> bf16, sinkhorn state init.
// Kernel boundary after this = device-scope release (proven rounds 0-2, 4, 5). --------
__global__ void __launch_bounds__(256) prep_kernel(const float* __restrict__ x,
                                                   const float* __restrict__ y,
                                                   ushort* __restrict__ xb,
                                                   ushort* __restrict__ yb,
                                                   float* __restrict__ nx,
                                                   float* __restrict__ ny,
                                                   const float* __restrict__ nu,
                                                   float* nup, float* colsum,
                                                   int* flagsi, float* out) {
  const int tid = threadIdx.x;
  int gt = blockIdx.x * 256 + tid;
  if (gt < BB * MM) {
    nup[gt] = nu[gt] + 1e-8f;
    colsum[4096 + gt] = 0.f;      // buf1 is iteration 0's add target
  }
  if (gt < 512) flagsi[gt] = 0;   // 2 x 128 ulong flag slots
  if (gt < BB) out[gt] = 0.f;

  const int w = tid >> 6, lane = tid & 63;
  const int r = blockIdx.x * 4 + w;                 // 0..8191
  const bool isx = (r < BB * NN);
  const float* src = isx ? (x + (size_t)r * DD)
                         : (y + (size_t)(r - BB * NN) * DD);
  ushort* dst = isx ? (xb + (size_t)r * DD)
                    : (yb + (size_t)(r - BB * NN) * DD);
  const float4* s4 = (const float4*)src;
  float4 a = s4[lane * 2];          // 8 contiguous floats per lane
  float4 b = s4[lane * 2 + 1];
  float ss = a.x * a.x + a.y * a.y + a.z * a.z + a.w * a.w +
             b.x * b.x + b.y * b.y + b.z * b.z + b.w * b.w;
  uint4 pk = make_uint4(pk2(a.x, a.y), pk2(a.z, a.w), pk2(b.x, b.y), pk2(b.z, b.w));
  *(uint4*)(dst + lane * 8) = pk;
  ss = wave_reduce_sum(ss);
  if (lane == 0) {
    float n = sqrtf(ss);
    if (isx) nx[r] = n; else ny[r - BB * NN] = n;
  }
}

// -------- fused strip-GEMM + persistent Sinkhorn (cooperative) --------
// phase 1: block computes its 32 K-rows (32x1024) into LDS via MFMA
//          (A staged in LDS, B streamed from L2); K never hits global.
// phase 2: EXACT round-1 sinkhorn (128 participants, 4 rows/wave in 64 VGPRs).
// NO XCD swizzle: identity block->batch mapping spreads each batch's 32 blocks
// across all 8 XCDs, so the per-iteration colsum atomics + flag traffic drain
// through 8 XCD->IOD paths instead of 2 (round-5 swizzle serialized them).
__global__ void __launch_bounds__(TBLK, 2) fused_kernel(
    const ushort* __restrict__ xb, const ushort* __restrict__ yb,
    const float* __restrict__ nx, const float* __restrict__ ny,
    float* __restrict__ colsum, const float* __restrict__ nup,
    u64* __restrict__ flags, float* __restrict__ out) {
  const int tid = threadIdx.x;
  const int bid = blockIdx.x;
  const int lane = tid & 63;
  const int w = tid >> 6;                 // 0..7
  const int m16 = lane & 15, q = lane >> 4;
  const int batch = bid >> 5;             // identity mapping (round-0/1 proven)
  const int rbase = (bid & 31) * 32;      // 32 owned rows

  __shared__ alignas(16) ushort As[32 * ALDA];      // 33.3 KB padded A stage
  __shared__ alignas(16) ushort kstrip[32 * KLDA];  // 66 KB K strip; spart alias
  __shared__ alignas(16) float s_v[1024];           // ny norms, then wv
  __shared__ float s_nx[32];
  __shared__ float s_red;
  __shared__ int s_conv;
  float* spart = (float*)kstrip;                    // [8][1024] in sinkhorn phase

  // ---------------- phase 1: strip GEMM into LDS ----------------
  {
    if (tid < 32) s_nx[tid] = nx[batch * NN + rbase + tid];
    s_v[tid] = ny[batch * MM + tid];
    s_v[tid + 512] = ny[batch * MM + tid + 512];

    // stage A strip (32 rows x 512 halves, contiguous in xb) into padded LDS
    {
      const ushort* xs = xb + ((size_t)batch * NN + rbase) * DD;
      const int row = tid >> 4;          // 16 threads per row
      const int c0 = (tid & 15) * 32;    // 32 halves (2 uint4 pairs x 2) each
#pragma unroll
      for (int i = 0; i < 4; ++i) {
        uint4 v = *(const uint4*)(xs + (size_t)row * DD + c0 + i * 8);
        *(uint4*)&As[row * ALDA + c0 + i * 8] = v;
      }
    }
    __syncthreads();

    // wave w owns cols [w*128, w*128+128), all 32 rows (2 row-tiles)
    const int j0 = w * 128;
    const ushort* brow = yb + ((size_t)batch * MM + j0 + m16) * DD + q * 8;
    f32x4 acc[2][8];
#pragma unroll
    for (int rt = 0; rt < 2; ++rt)
#pragma unroll
      for (int ni = 0; ni < 8; ++ni) acc[rt][ni] = (f32x4)0.f;

#pragma unroll
    for (int ks = 0; ks < 16; ++ks) {
      bf16x8 a0 = *(const bf16x8*)&As[(m16)*ALDA + ks * 32 + q * 8];
      bf16x8 a1 = *(const bf16x8*)&As[(16 + m16) * ALDA + ks * 32 + q * 8];
      bf16x8 bfr[8];
#pragma unroll
      for (int ni = 0; ni < 8; ++ni)
        bfr[ni] = *(const bf16x8*)(brow + (size_t)ni * 16 * DD + ks * 32);
#pragma unroll
      for (int ni = 0; ni < 8; ++ni)
        acc[0][ni] = __builtin_amdgcn_mfma_f32_16x16x32_bf16(a0, bfr[ni], acc[0][ni], 0, 0, 0);
#pragma unroll
      for (int ni = 0; ni < 8; ++ni)
        acc[1][ni] = __builtin_amdgcn_mfma_f32_16x16x32_bf16(a1, bfr[ni], acc[1][ni], 0, 0, 0);
    }

    // epilogue: K = exp(-(1 - dot/den)/eps) -> LDS bf16 (kstrip region untouched
    // so far; As is dead; s_nx/s_v were staged before the first barrier)
#pragma unroll
    for (int rt = 0; rt < 2; ++rt)
#pragma unroll
      for (int ni = 0; ni < 8; ++ni)
#pragma unroll
        for (int r = 0; r < 4; ++r) {
          const int row = rt * 16 + q * 4 + r;
          const int col = j0 + ni * 16 + m16;
          float den = fmaxf(s_nx[row] * s_v[col], 1e-8f);
          float cv = 1.0f - acc[rt][ni][r] / den;
          float kv = __expf(-cv * INV_EPS);
          __bf16 hb = (__bf16)kv;
          kstrip[row * KLDA + col] = *(ushort*)&hb;
        }
    __syncthreads();   // strip complete before cross-wave per-wave reg loads
  }

  // ---- each wave loads its 4 rows into registers (64 VGPR), fp32 ----
  float kfr[4][16];
#pragma unroll
  for (int rr = 0; rr < 4; ++rr) {
    const int base = (w * 4 + rr) * KLDA;
    uint4 p;
    p = *(const uint4*)&kstrip[base + 8 * lane];       unpack8(p, kfr[rr]);
    p = *(const uint4*)&kstrip[base + 512 + 8 * lane]; unpack8(p, kfr[rr] + 8);
  }
  // kstrip memory is reused as spart[8][1024] from here on; the __syncthreads()
  // after wv staging in iteration 0 orders spart writes after the kfr reads.

  // ---------------- phase 2: persistent Sinkhorn (round-1 verbatim) ----------------
  const float eps_log_mu = EPS * __logf(MU_P);
  float u_prev[4] = {0.f, 0.f, 0.f, 0.f};
  float wu_reg[4] = {0.f, 0.f, 0.f, 0.f};
  int T = 0;

  for (int it = 0; it < MAX_IT; ++it) {
    const int genv = it + 1;
    if (tid == 0) s_red = 0.f;
    if (it == 0) {
      s_v[tid] = 1.f;
      s_v[tid + 512] = 1.f;
    } else {
      const float* cs = colsum + (it % 3) * 4096 + batch * MM;
      float c0 = __hip_atomic_load(cs + tid, __ATOMIC_RELAXED, __HIP_MEMORY_SCOPE_AGENT);
      float c1 = __hip_atomic_load(cs + tid + 512, __ATOMIC_RELAXED, __HIP_MEMORY_SCOPE_AGENT);
      s_v[tid] = nup[batch * MM + tid] / c0;
      s_v[tid + 512] = nup[batch * MM + tid + 512] / c1;
    }
    __syncthreads();

    float wvr[16];
    {
      const float4* wp = (const float4*)s_v;
      *(float4*)&wvr[0] = wp[lane * 2];
      *(float4*)&wvr[4] = wp[lane * 2 + 1];
      *(float4*)&wvr[8] = wp[128 + lane * 2];
      *(float4*)&wvr[12] = wp[129 + lane * 2];
    }
    float creg[16];
#pragma unroll
    for (int t2 = 0; t2 < 16; ++t2) creg[t2] = 0.f;

    float werr = 0.f;
#pragma unroll
    for (int rr = 0; rr < 4; ++rr) {
      float s = 0.f;
#pragma unroll
      for (int t2 = 0; t2 < 16; ++t2) s = fmaf(kfr[rr][t2], wvr[t2], s);
      s = wave_reduce_sum(s);
      float unv = eps_log_mu - EPS * __logf(s);
      werr += fabsf(unv - u_prev[rr]);
      u_prev[rr] = unv;
      float wu = MU_P / s;              // exp(u_new/eps), exactly
      wu_reg[rr] = wu;
#pragma unroll
      for (int t2 = 0; t2 < 16; ++t2) creg[t2] = fmaf(wu, kfr[rr][t2], creg[t2]);
    }
    if (lane == 0) atomicAdd(&s_red, werr);

    // publish per-wave column partials to LDS (aliased kstrip)
    {
      float* pr = spart + w * 1024;
      *(float4*)&pr[lane * 8] = *(float4*)&creg[0];
      *(float4*)&pr[lane * 8 + 4] = *(float4*)&creg[4];
      *(float4*)&pr[512 + lane * 8] = *(float4*)&creg[8];
      *(float4*)&pr[512 + lane * 8 + 4] = *(float4*)&creg[12];
    }
    __syncthreads();

    // cross-wave reduce + atomic add into next colsum; zero rotation buffer
    {
      float* csn = colsum + ((it + 1) % 3) * 4096 + batch * MM;
      const int j0 = tid * 2;
      float s0 = 0.f, s1 = 0.f;
#pragma unroll
      for (int ww = 0; ww < 8; ++ww) {
        float2 p = *(const float2*)&spart[ww * 1024 + j0];
        s0 += p.x;
        s1 += p.y;
      }
      unsafeAtomicAdd(&csn[j0], s0);
      unsafeAtomicAdd(&csn[j0 + 1], s1);
      if (tid < 32) {
        float* csz = colsum + ((it + 2) % 3) * 4096;
        __hip_atomic_store(&csz[bid * 32 + tid], 0.f, __ATOMIC_RELAXED, __HIP_MEMORY_SCOPE_AGENT);
      }
    }

    // ---- all-to-all barrier: publish {gen, err}, poll, local conv decision ----
    asm volatile("s_waitcnt vmcnt(0)" ::: "memory");
    __syncthreads();
    if (tid == 0) {
      u64 f = ((u64)(uint)genv << 32) | (u64)__float_as_uint(s_red);
      __hip_atomic_store(&flags[(genv & 1) * GBLK + bid], f, __ATOMIC_RELAXED, __HIP_MEMORY_SCOPE_AGENT);
    }
    if (tid < 64) {
      const u64* fl = flags + (genv & 1) * GBLK;
      u64 f0, f1;
      for (;;) {
        f0 = __hip_atomic_load(fl + tid, __ATOMIC_RELAXED, __HIP_MEMORY_SCOPE_AGENT);
        f1 = __hip_atomic_load(fl + tid + 64, __ATOMIC_RELAXED, __HIP_MEMORY_SCOPE_AGENT);
        if (__all(((f0 >> 32) >= (u64)genv) && ((f1 >> 32) >= (u64)genv))) break;
        __builtin_amdgcn_s_sleep(1);
      }
      float e = __uint_as_float((uint)f0) + __uint_as_float((uint)f1);
      e = wave_reduce_sum(e);
      if (tid == 0) s_conv = (e * (1.0f / (float)BB) < THRESH) ? 1 : 0;
    }
    __syncthreads();
    T = it;
    if (s_conv) break;
  }

  // ---- final: reconstruct converged wv locally, accumulate transport cost ----
  {
    const float* cs = colsum + ((T + 1) % 3) * 4096 + batch * MM;
    float c0 = __hip_atomic_load(cs + tid, __ATOMIC_RELAXED, __HIP_MEMORY_SCOPE_AGENT);
    float c1 = __hip_atomic_load(cs + tid + 512, __ATOMIC_RELAXED, __HIP_MEMORY_SCOPE_AGENT);
    s_v[tid] = nup[batch * MM + tid] / c0;
    s_v[tid + 512] = nup[batch * MM + tid + 512] / c1;
  }
  if (tid == 0) s_red = 0.f;
  __syncthreads();

  float wvr[16];
  {
    const float4* wp = (const float4*)s_v;
    *(float4*)&wvr[0] = wp[lane * 2];
    *(float4*)&wvr[4] = wp[lane * 2 + 1];
    *(float4*)&wvr[8] = wp[128 + lane * 2];
    *(float4*)&wvr[12] = wp[129 + lane * 2];
  }

  float wcost = 0.f;
#pragma unroll
  for (int rr = 0; rr < 4; ++rr) {
    float s = 0.f;
#pragma unroll
    for (int t2 = 0; t2 < 16; ++t2)
      s = fmaf(kfr[rr][t2] * wvr[t2], -EPS * __logf(kfr[rr][t2]), s);  // pi*C, C=-eps log K
    s = wave_reduce_sum(s) * wu_reg[rr];
    if (lane == 0) wcost += s;
  }
  if (lane == 0) atomicAdd(&s_red, wcost);
  __syncthreads();
  if (tid == 0) atomicAdd(out + batch, s_red);
}

extern "C" void kernel_launch(void* const* d_in, const int* in_sizes, int n_in,
                              void* d_out, int out_size, void* d_ws, size_t ws_size,
                              hipStream_t stream) {
  const float* x = (const float*)d_in[0];
  const float* y = (const float*)d_in[1];
  const float* nu = (const float*)d_in[2];
  float* out = (float*)d_out;
  float* ws = (float*)d_ws;

  ushort* xb = (ushort*)(ws + OFF_XB);
  ushort* yb = (ushort*)(ws + OFF_YB);
  float* nx = ws + OFF_NX;
  float* ny = ws + OFF_NY;
  float* nup = ws + OFF_NUP;
  float* cs = ws + OFF_CS;
  u64* flg = (u64*)(ws + OFF_FLG);

  prep_kernel<<<2048, 256, 0, stream>>>(x, y, xb, yb, nx, ny, nu, nup, cs,
                                        (int*)flg, out);

  void* args[] = {(void*)&xb, (void*)&yb, (void*)&nx,  (void*)&ny,
                  (void*)&cs, (void*)&nup, (void*)&flg, (void*)&out};
  hipLaunchCooperativeKernel(reinterpret_cast<void*>(&fused_kernel),
                             dim3(GBLK), dim3(TBLK), args, 0, stream);
}